// Round 1
// baseline (713.141 us; speedup 1.0000x reference)
//
#include <hip/hip_runtime.h>
#include <hip/hip_bf16.h>
#include <math.h>

#define T_TOK   8192
#define D_MODEL 1024
#define DFFN    2048
#define N_EXP   8
#define NASSIGN (T_TOK*2)

#define BM 128
#define BN 128
#define BK 32
#define BKP 40          // padded K-extent per LDS row (elements); 80B stride, 16B aligned
#define TILE_MAX 144

// ---- workspace layout (byte offsets) ----
#define WS_ZSUM     0        // float
#define WS_PSUM     4        // 8 floats
#define WS_COUNTS   64       // 8 ints
#define WS_CURSOR   96       // 8 ints
#define WS_OFFS     128      // 8 ints
#define WS_NTILES   160      // int
#define WS_TMAP     256      // TILE_MAX * 4 ints (e, gr, valid, pad)
#define WS_SEL      4096     // NASSIGN ints
#define WS_WGT      69632    // NASSIGN floats
#define WS_AIDX     135168   // NASSIGN ints
#define WS_AW       200704   // NASSIGN floats
#define WS_H        266240   // NASSIGN*DFFN ushort (bf16), 64 MB

typedef __attribute__((ext_vector_type(8))) short bf16x8;
typedef __attribute__((ext_vector_type(4))) float f32x4;
typedef __attribute__((ext_vector_type(4))) unsigned int u32x4;

static __device__ __forceinline__ unsigned short f2bf(float f) {
    unsigned int u = __builtin_bit_cast(unsigned int, f);
    u += 0x7fffu + ((u >> 16) & 1u);
    return (unsigned short)(u >> 16);
}

// ---------------- router ----------------
// 32 tokens per block, 8 threads per token (one per expert).
__global__ __launch_bounds__(256) void router_kernel(
    const float* __restrict__ x, const float* __restrict__ rw,
    float* zsum, float* psum, int* counts, int* sel, float* wgt)
{
    __shared__ float xs[32*129];
    __shared__ float rs[8*129];
    __shared__ float lg[32*9];
    __shared__ float blk_p[8];
    __shared__ int   blk_c[8];
    __shared__ float blk_z;
    int tid = threadIdx.x;
    if (tid < 8) { blk_p[tid] = 0.f; blk_c[tid] = 0; }
    if (tid == 8) blk_z = 0.f;
    int tb = blockIdx.x * 32;
    int tt = tid >> 3, e = tid & 7;
    float acc = 0.f;
    for (int c = 0; c < 8; ++c) {
        int c0 = c * 128;
        #pragma unroll
        for (int p = 0; p < 16; ++p) {
            int flat = p * 256 + tid;
            int r = flat >> 7, col = flat & 127;
            xs[r*129 + col] = x[(size_t)(tb + r)*D_MODEL + c0 + col];
        }
        #pragma unroll
        for (int p = 0; p < 4; ++p) {
            int flat = p * 256 + tid;
            int er = flat >> 7, col = flat & 127;
            rs[er*129 + col] = rw[(size_t)er*D_MODEL + c0 + col];
        }
        __syncthreads();
        #pragma unroll 8
        for (int i = 0; i < 128; ++i)
            acc += xs[tt*129 + i] * rs[e*129 + i];
        __syncthreads();
    }
    lg[tt*9 + e] = acc;
    __syncthreads();
    if (tid < 32) {
        int t = tb + tid;
        float l[8], p[8];
        float mx = -1e30f;
        #pragma unroll
        for (int j = 0; j < 8; ++j) { l[j] = lg[tid*9 + j]; mx = fmaxf(mx, l[j]); }
        float se = 0.f;
        #pragma unroll
        for (int j = 0; j < 8; ++j) { p[j] = expf(l[j] - mx); se += p[j]; }
        float inv = 1.f / se;
        #pragma unroll
        for (int j = 0; j < 8; ++j) p[j] *= inv;
        float lse = mx + logf(se);
        atomicAdd(&blk_z, lse*lse);
        #pragma unroll
        for (int j = 0; j < 8; ++j) atomicAdd(&blk_p[j], p[j]);
        // top-2 (ties -> lower index, matching lax.top_k)
        int i0 = 0; float b0 = p[0];
        #pragma unroll
        for (int j = 1; j < 8; ++j) if (p[j] > b0) { b0 = p[j]; i0 = j; }
        int i1 = -1; float b1 = -1.f;
        #pragma unroll
        for (int j = 0; j < 8; ++j) if (j != i0 && p[j] > b1) { b1 = p[j]; i1 = j; }
        float s = b0 + b1;
        sel[t*2+0] = i0; sel[t*2+1] = i1;
        wgt[t*2+0] = b0 / s; wgt[t*2+1] = b1 / s;
        atomicAdd(&blk_c[i0], 1); atomicAdd(&blk_c[i1], 1);
    }
    __syncthreads();
    if (tid < 8) {
        atomicAdd(&counts[tid], blk_c[tid]);
        unsafeAtomicAdd(&psum[tid], blk_p[tid]);
    }
    if (tid == 8) unsafeAtomicAdd(zsum, blk_z);
}

// ---------------- offsets + tile map + aux-loss scalars ----------------
__global__ void finalize_kernel(const int* counts, const float* psum, const float* zsum,
                                int* offs, int* ntiles, int* tmap, float* out_tail)
{
    if (threadIdx.x != 0) return;
    int off = 0, nt = 0;
    float lb = 0.f;
    for (int e = 0; e < N_EXP; ++e) {
        int c = counts[e];
        offs[e] = off;
        for (int m0 = 0; m0 < c; m0 += BM) {
            tmap[nt*4+0] = e;
            tmap[nt*4+1] = off + m0;
            tmap[nt*4+2] = min(BM, c - m0);
            tmap[nt*4+3] = 0;
            nt++;
        }
        float fi = (float)c / (float)NASSIGN;
        out_tail[2 + e] = fi;
        lb += fi * (psum[e] / (float)T_TOK);
        off += c;
    }
    *ntiles = nt;
    out_tail[0] = zsum[0] / (float)T_TOK;
    out_tail[1] = (float)N_EXP * lb;
}

// ---------------- scatter tokens into per-expert segments ----------------
__global__ __launch_bounds__(256) void scatter_kernel(
    const int* __restrict__ sel, const float* __restrict__ wgt,
    const int* __restrict__ offs, int* cursor, int* aidx, float* aw)
{
    int t = blockIdx.x * 256 + threadIdx.x;
    if (t >= T_TOK) return;
    #pragma unroll
    for (int k = 0; k < 2; ++k) {
        int e = sel[t*2 + k];
        int pos = atomicAdd(&cursor[e], 1);
        int r = offs[e] + pos;
        aidx[r] = t;
        aw[r] = wgt[t*2 + k];
    }
}

// ---------------- GEMM1: H = gelu(Xg @ W1_e), bf16 out ----------------
__global__ __launch_bounds__(256) void gemm1_kernel(
    const float* __restrict__ x, const float* __restrict__ w1,
    const int* __restrict__ aidx, const int* __restrict__ tmap,
    const int* __restrict__ ntiles, unsigned short* __restrict__ H)
{
    int tile = blockIdx.y;
    if (tile >= *ntiles) return;
    int e     = tmap[tile*4+0];
    int gr    = tmap[tile*4+1];
    int valid = tmap[tile*4+2];
    int n0 = blockIdx.x * BN;      // within expert's DFFN cols
    __shared__ unsigned short As[BM*BKP];
    __shared__ unsigned short Bs[BN*BKP];   // transposed: [n][k]
    int tid = threadIdx.x;
    int lane = tid & 63, wave = tid >> 6;
    int wm = (wave & 1) * 64, wn = (wave >> 1) * 64;
    int q = lane >> 4, r16 = lane & 15;
    f32x4 acc[4][4];
    #pragma unroll
    for (int i = 0; i < 4; ++i) {
        #pragma unroll
        for (int j = 0; j < 4; ++j) acc[i][j] = (f32x4){0.f, 0.f, 0.f, 0.f};
    }
    int arow = tid >> 3;            // 0..31 (m within 32-row pass)
    int ac4  = (tid & 7) * 4;       // k group of 4
    int rowtok[4];
    #pragma unroll
    for (int p = 0; p < 4; ++p) {
        int m = arow + p*32;
        rowtok[p] = aidx[gr + min(m, valid - 1)];
    }
    int bn  = tid & 127;            // B stage: n index
    int bkq = (tid >> 7) * 16;      // 0 or 16
    const size_t bcol = (size_t)e * DFFN + n0 + bn;

    for (int kt = 0; kt < D_MODEL / BK; ++kt) {
        int k0 = kt * BK;
        // stage A (gathered x rows, fp32 -> bf16)
        #pragma unroll
        for (int p = 0; p < 4; ++p) {
            int m = arow + p*32;
            const float4 v = *(const float4*)(x + (size_t)rowtok[p]*D_MODEL + k0 + ac4);
            ushort4 h;
            h.x = f2bf(v.x); h.y = f2bf(v.y); h.z = f2bf(v.z); h.w = f2bf(v.w);
            *(ushort4*)&As[m*BKP + ac4] = h;
        }
        // stage B transposed (coalesced fp32 loads, ushort4 column writes)
        #pragma unroll
        for (int p = 0; p < 4; ++p) {
            int kb = bkq + p*4;
            float v0 = w1[(size_t)(k0 + kb + 0)*(N_EXP*DFFN) + bcol];
            float v1 = w1[(size_t)(k0 + kb + 1)*(N_EXP*DFFN) + bcol];
            float v2 = w1[(size_t)(k0 + kb + 2)*(N_EXP*DFFN) + bcol];
            float v3 = w1[(size_t)(k0 + kb + 3)*(N_EXP*DFFN) + bcol];
            ushort4 h;
            h.x = f2bf(v0); h.y = f2bf(v1); h.z = f2bf(v2); h.w = f2bf(v3);
            *(ushort4*)&Bs[bn*BKP + kb] = h;
        }
        __syncthreads();
        bf16x8 af[4], bfr[4];
        #pragma unroll
        for (int im = 0; im < 4; ++im)
            af[im] = *(const bf16x8*)&As[(wm + im*16 + r16)*BKP + q*8];
        #pragma unroll
        for (int in = 0; in < 4; ++in)
            bfr[in] = *(const bf16x8*)&Bs[(wn + in*16 + r16)*BKP + q*8];
        #pragma unroll
        for (int im = 0; im < 4; ++im) {
            #pragma unroll
            for (int in = 0; in < 4; ++in)
                acc[im][in] = __builtin_amdgcn_mfma_f32_16x16x32_bf16(af[im], bfr[in], acc[im][in], 0, 0, 0);
        }
        __syncthreads();
    }
    // epilogue: exact gelu, store bf16
    #pragma unroll
    for (int im = 0; im < 4; ++im) {
        #pragma unroll
        for (int reg = 0; reg < 4; ++reg) {
            int m = wm + im*16 + q*4 + reg;
            if (m < valid) {
                size_t rowbase = (size_t)(gr + m) * DFFN + n0 + wn;
                #pragma unroll
                for (int in = 0; in < 4; ++in) {
                    float v = acc[im][in][reg];
                    float g = 0.5f * v * (1.0f + erff(v * 0.70710678118654752f));
                    H[rowbase + in*16 + r16] = f2bf(g);
                }
            }
        }
    }
}

// ---------------- GEMM2: out[t] += w * (H_row @ W2_e) ----------------
__global__ __launch_bounds__(256) void gemm2_kernel(
    const unsigned short* __restrict__ H, const float* __restrict__ w2,
    const int* __restrict__ aidx, const float* __restrict__ aw,
    const int* __restrict__ tmap, const int* __restrict__ ntiles,
    float* __restrict__ out)
{
    int tile = blockIdx.y;
    if (tile >= *ntiles) return;
    int e     = tmap[tile*4+0];
    int gr    = tmap[tile*4+1];
    int valid = tmap[tile*4+2];
    int n0 = blockIdx.x * BN;      // within D_MODEL
    __shared__ unsigned short As[BM*BKP];
    __shared__ unsigned short Bs[BN*BKP];   // transposed: [n][k]
    int tid = threadIdx.x;
    int lane = tid & 63, wave = tid >> 6;
    int wm = (wave & 1) * 64, wn = (wave >> 1) * 64;
    int q = lane >> 4, r16 = lane & 15;
    f32x4 acc[4][4];
    #pragma unroll
    for (int i = 0; i < 4; ++i) {
        #pragma unroll
        for (int j = 0; j < 4; ++j) acc[i][j] = (f32x4){0.f, 0.f, 0.f, 0.f};
    }
    int am = tid >> 1, ah = (tid & 1) * 16;       // row, 16-elem half
    int amr = min(am, valid - 1);
    const unsigned short* hrow = H + (size_t)(gr + amr)*DFFN + ah;
    int bn  = tid & 127;
    int bkq = (tid >> 7) * 16;
    const size_t bcol = n0 + bn;

    for (int kt = 0; kt < DFFN / BK; ++kt) {
        int k0 = kt * BK;
        // stage A (already bf16): two 16B copies per thread
        {
            const u32x4 v0 = *(const u32x4*)(hrow + k0);
            const u32x4 v1 = *(const u32x4*)(hrow + k0 + 8);
            *(u32x4*)&As[am*BKP + ah]     = v0;
            *(u32x4*)&As[am*BKP + ah + 8] = v1;
        }
        // stage B transposed
        #pragma unroll
        for (int p = 0; p < 4; ++p) {
            int kb = bkq + p*4;
            float v0 = w2[(size_t)(e*DFFN + k0 + kb + 0)*D_MODEL + bcol];
            float v1 = w2[(size_t)(e*DFFN + k0 + kb + 1)*D_MODEL + bcol];
            float v2 = w2[(size_t)(e*DFFN + k0 + kb + 2)*D_MODEL + bcol];
            float v3 = w2[(size_t)(e*DFFN + k0 + kb + 3)*D_MODEL + bcol];
            ushort4 h;
            h.x = f2bf(v0); h.y = f2bf(v1); h.z = f2bf(v2); h.w = f2bf(v3);
            *(ushort4*)&Bs[bn*BKP + kb] = h;
        }
        __syncthreads();
        bf16x8 af[4], bfr[4];
        #pragma unroll
        for (int im = 0; im < 4; ++im)
            af[im] = *(const bf16x8*)&As[(wm + im*16 + r16)*BKP + q*8];
        #pragma unroll
        for (int in = 0; in < 4; ++in)
            bfr[in] = *(const bf16x8*)&Bs[(wn + in*16 + r16)*BKP + q*8];
        #pragma unroll
        for (int im = 0; im < 4; ++im) {
            #pragma unroll
            for (int in = 0; in < 4; ++in)
                acc[im][in] = __builtin_amdgcn_mfma_f32_16x16x32_bf16(af[im], bfr[in], acc[im][in], 0, 0, 0);
        }
        __syncthreads();
    }
    // epilogue: weighted scatter-add into output
    #pragma unroll
    for (int im = 0; im < 4; ++im) {
        #pragma unroll
        for (int reg = 0; reg < 4; ++reg) {
            int m = wm + im*16 + q*4 + reg;
            if (m < valid) {
                int t = aidx[gr + m];
                float w = aw[gr + m];
                float* orow = out + (size_t)t*D_MODEL + n0 + wn;
                #pragma unroll
                for (int in = 0; in < 4; ++in)
                    unsafeAtomicAdd(&orow[in*16 + r16], w * acc[im][in][reg]);
            }
        }
    }
}

extern "C" void kernel_launch(void* const* d_in, const int* in_sizes, int n_in,
                              void* d_out, int out_size, void* d_ws, size_t ws_size,
                              hipStream_t stream)
{
    const float* x  = (const float*)d_in[0];
    const float* rw = (const float*)d_in[1];
    const float* w1 = (const float*)d_in[2];
    const float* w2 = (const float*)d_in[3];
    float* out = (float*)d_out;
    char* ws = (char*)d_ws;
    float* zsum   = (float*)(ws + WS_ZSUM);
    float* psum   = (float*)(ws + WS_PSUM);
    int*   counts = (int*)(ws + WS_COUNTS);
    int*   cursor = (int*)(ws + WS_CURSOR);
    int*   offs   = (int*)(ws + WS_OFFS);
    int*   ntiles = (int*)(ws + WS_NTILES);
    int*   tmap   = (int*)(ws + WS_TMAP);
    int*   sel    = (int*)(ws + WS_SEL);
    float* wgt    = (float*)(ws + WS_WGT);
    int*   aidx   = (int*)(ws + WS_AIDX);
    float* aw     = (float*)(ws + WS_AW);
    unsigned short* H = (unsigned short*)(ws + WS_H);

    // zero accumulators + output region (ws/out are poisoned before every call)
    hipMemsetAsync(d_out, 0, (size_t)T_TOK * D_MODEL * sizeof(float), stream);
    hipMemsetAsync(ws, 0, 256, stream);

    router_kernel<<<T_TOK/32, 256, 0, stream>>>(x, rw, zsum, psum, counts, sel, wgt);
    finalize_kernel<<<1, 64, 0, stream>>>(counts, psum, zsum, offs, ntiles, tmap,
                                          out + (size_t)T_TOK * D_MODEL);
    scatter_kernel<<<T_TOK/256, 256, 0, stream>>>(sel, wgt, offs, cursor, aidx, aw);
    gemm1_kernel<<<dim3(DFFN/BN, TILE_MAX), 256, 0, stream>>>(x, w1, aidx, tmap, ntiles, H);
    gemm2_kernel<<<dim3(D_MODEL/BN, TILE_MAX), 256, 0, stream>>>(H, w2, aidx, aw, tmap, ntiles, out);
}

// Round 2
// 613.196 us; speedup vs baseline: 1.1630x; 1.1630x over previous
//
#include <hip/hip_runtime.h>
#include <hip/hip_bf16.h>
#include <math.h>

#define T_TOK   8192
#define D_MODEL 1024
#define DFFN    2048
#define N_EXP   8
#define NASSIGN (T_TOK*2)

#define BM 128
#define BN 128
#define BK 32
#define TILE_MAX 144

// ---- workspace layout (byte offsets) ----
#define WS_ZSUM     0        // float
#define WS_PSUM     4        // 8 floats
#define WS_COUNTS   64       // 8 ints
#define WS_CURSOR   96       // 8 ints
#define WS_OFFS     128      // 8 ints
#define WS_NTILES   160      // int
#define WS_TMAP     256      // TILE_MAX * 4 ints (e, gr, valid, pad)
#define WS_SEL      4096     // NASSIGN ints
#define WS_WGT      69632    // NASSIGN floats
#define WS_AIDX     135168   // NASSIGN ints
#define WS_AW       200704   // NASSIGN floats
#define WS_XB       266240                    // T_TOK*D_MODEL bf16   (16 MB)
#define WS_W1T      (WS_XB + 16777216)        // [e][n][k] bf16       (32 MB)
#define WS_W2T      (WS_W1T + 33554432)       // [e][n][k] bf16       (32 MB)
#define WS_H        (WS_W2T + 33554432)       // NASSIGN*DFFN bf16    (64 MB)
// total ≈ 151.3 MB

typedef __attribute__((ext_vector_type(8))) short bf16x8;
typedef __attribute__((ext_vector_type(4))) float f32x4;
typedef __attribute__((ext_vector_type(4))) unsigned int u32x4;

static __device__ __forceinline__ unsigned short f2bf(float f) {
    unsigned int u = __builtin_bit_cast(unsigned int, f);
    u += 0x7fffu + ((u >> 16) & 1u);
    return (unsigned short)(u >> 16);
}

// async global->LDS, 16B per lane; LDS dest = wave-uniform base + lane*16.
// We pass each lane's own lds addr (lane0's value is the wave base).
static __device__ __forceinline__ void gll16(const unsigned short* g, unsigned short* l) {
    __builtin_amdgcn_global_load_lds(
        (const __attribute__((address_space(1))) unsigned int*)g,
        (__attribute__((address_space(3))) unsigned int*)l, 16, 0, 0);
}

// ---------------- one-shot converts ----------------
__global__ __launch_bounds__(256) void cvt_x_kernel(const float* __restrict__ in,
                                                    unsigned short* __restrict__ out)
{
    int i = (blockIdx.x * 256 + threadIdx.x) * 8;
    float4 a = *(const float4*)(in + i);
    float4 b = *(const float4*)(in + i + 4);
    unsigned short t[8];
    t[0]=f2bf(a.x); t[1]=f2bf(a.y); t[2]=f2bf(a.z); t[3]=f2bf(a.w);
    t[4]=f2bf(b.x); t[5]=f2bf(b.y); t[6]=f2bf(b.z); t[7]=f2bf(b.w);
    *(u32x4*)(out + i) = *(u32x4*)t;
}

// in: [E][K][N] fp32 -> out: [E][N][K] bf16 (64x64 tiles)
__global__ __launch_bounds__(256) void transpose_cvt_kernel(
    const float* __restrict__ in, unsigned short* __restrict__ out, int K, int N)
{
    int e = blockIdx.z;
    const float* inp = in + (size_t)e * K * N;
    unsigned short* outp = out + (size_t)e * K * N;
    __shared__ unsigned short tile[64][68];
    int k0 = blockIdx.y * 64, n0 = blockIdx.x * 64;
    int tid = threadIdx.x;
    int r = tid >> 4, c4 = (tid & 15) * 4;
    #pragma unroll
    for (int p = 0; p < 4; ++p) {
        int k = r + p * 16;
        float4 v = *(const float4*)(inp + (size_t)(k0 + k) * N + n0 + c4);
        tile[k][c4+0] = f2bf(v.x);
        tile[k][c4+1] = f2bf(v.y);
        tile[k][c4+2] = f2bf(v.z);
        tile[k][c4+3] = f2bf(v.w);
    }
    __syncthreads();
    int n = tid >> 2, kc = (tid & 3) * 16;
    unsigned short t[16];
    #pragma unroll
    for (int j = 0; j < 16; ++j) t[j] = tile[kc + j][n];
    unsigned short* o = outp + (size_t)(n0 + n) * K + k0 + kc;
    *(u32x4*)o       = *(u32x4*)t;
    *(u32x4*)(o + 8) = *(u32x4*)(t + 8);
}

// ---------------- router ----------------
__global__ __launch_bounds__(256) void router_kernel(
    const float* __restrict__ x, const float* __restrict__ rw,
    float* zsum, float* psum, int* counts, int* sel, float* wgt)
{
    __shared__ float xs[32*129];
    __shared__ float rs[8*129];
    __shared__ float lg[32*9];
    __shared__ float blk_p[8];
    __shared__ int   blk_c[8];
    __shared__ float blk_z;
    int tid = threadIdx.x;
    if (tid < 8) { blk_p[tid] = 0.f; blk_c[tid] = 0; }
    if (tid == 8) blk_z = 0.f;
    int tb = blockIdx.x * 32;
    int tt = tid >> 3, e = tid & 7;
    float acc = 0.f;
    for (int c = 0; c < 8; ++c) {
        int c0 = c * 128;
        #pragma unroll
        for (int p = 0; p < 16; ++p) {
            int flat = p * 256 + tid;
            int r = flat >> 7, col = flat & 127;
            xs[r*129 + col] = x[(size_t)(tb + r)*D_MODEL + c0 + col];
        }
        #pragma unroll
        for (int p = 0; p < 4; ++p) {
            int flat = p * 256 + tid;
            int er = flat >> 7, col = flat & 127;
            rs[er*129 + col] = rw[(size_t)er*D_MODEL + c0 + col];
        }
        __syncthreads();
        #pragma unroll 8
        for (int i = 0; i < 128; ++i)
            acc += xs[tt*129 + i] * rs[e*129 + i];
        __syncthreads();
    }
    lg[tt*9 + e] = acc;
    __syncthreads();
    if (tid < 32) {
        int t = tb + tid;
        float l[8], p[8];
        float mx = -1e30f;
        #pragma unroll
        for (int j = 0; j < 8; ++j) { l[j] = lg[tid*9 + j]; mx = fmaxf(mx, l[j]); }
        float se = 0.f;
        #pragma unroll
        for (int j = 0; j < 8; ++j) { p[j] = expf(l[j] - mx); se += p[j]; }
        float inv = 1.f / se;
        #pragma unroll
        for (int j = 0; j < 8; ++j) p[j] *= inv;
        float lse = mx + logf(se);
        atomicAdd(&blk_z, lse*lse);
        #pragma unroll
        for (int j = 0; j < 8; ++j) atomicAdd(&blk_p[j], p[j]);
        int i0 = 0; float b0 = p[0];
        #pragma unroll
        for (int j = 1; j < 8; ++j) if (p[j] > b0) { b0 = p[j]; i0 = j; }
        int i1 = -1; float b1 = -1.f;
        #pragma unroll
        for (int j = 0; j < 8; ++j) if (j != i0 && p[j] > b1) { b1 = p[j]; i1 = j; }
        float s = b0 + b1;
        sel[t*2+0] = i0; sel[t*2+1] = i1;
        wgt[t*2+0] = b0 / s; wgt[t*2+1] = b1 / s;
        atomicAdd(&blk_c[i0], 1); atomicAdd(&blk_c[i1], 1);
    }
    __syncthreads();
    if (tid < 8) {
        atomicAdd(&counts[tid], blk_c[tid]);
        unsafeAtomicAdd(&psum[tid], blk_p[tid]);
    }
    if (tid == 8) unsafeAtomicAdd(zsum, blk_z);
}

// ---------------- offsets + tile map + aux-loss scalars ----------------
__global__ void finalize_kernel(const int* counts, const float* psum, const float* zsum,
                                int* offs, int* ntiles, int* tmap, float* out_tail)
{
    if (threadIdx.x != 0) return;
    int off = 0, nt = 0;
    float lb = 0.f;
    for (int e = 0; e < N_EXP; ++e) {
        int c = counts[e];
        offs[e] = off;
        for (int m0 = 0; m0 < c; m0 += BM) {
            tmap[nt*4+0] = e;
            tmap[nt*4+1] = off + m0;
            tmap[nt*4+2] = min(BM, c - m0);
            tmap[nt*4+3] = 0;
            nt++;
        }
        float fi = (float)c / (float)NASSIGN;
        out_tail[2 + e] = fi;
        lb += fi * (psum[e] / (float)T_TOK);
        off += c;
    }
    *ntiles = nt;
    out_tail[0] = zsum[0] / (float)T_TOK;
    out_tail[1] = (float)N_EXP * lb;
}

// ---------------- scatter tokens into per-expert segments ----------------
__global__ __launch_bounds__(256) void scatter_kernel(
    const int* __restrict__ sel, const float* __restrict__ wgt,
    const int* __restrict__ offs, int* cursor, int* aidx, float* aw)
{
    int t = blockIdx.x * 256 + threadIdx.x;
    if (t >= T_TOK) return;
    #pragma unroll
    for (int k = 0; k < 2; ++k) {
        int e = sel[t*2 + k];
        int pos = atomicAdd(&cursor[e], 1);
        int r = offs[e] + pos;
        aidx[r] = t;
        aw[r] = wgt[t*2 + k];
    }
}

// ---------------- GEMM1: H = gelu(Xg @ W1_e), bf16 out ----------------
// A: gathered xb rows (bf16). B: w1t [e][n][k] bf16. LDS unpadded [row][32].
__global__ __launch_bounds__(256) void gemm1_kernel(
    const unsigned short* __restrict__ xb, const unsigned short* __restrict__ w1t,
    const int* __restrict__ aidx, const int* __restrict__ tmap,
    const int* __restrict__ ntiles, unsigned short* __restrict__ H)
{
    int tile = blockIdx.y;
    if (tile >= *ntiles) return;
    int e     = tmap[tile*4+0];
    int gr    = tmap[tile*4+1];
    int valid = tmap[tile*4+2];
    int n0 = blockIdx.x * BN;
    __shared__ unsigned short As[BM*BK];
    __shared__ unsigned short Bs[BN*BK];
    int tid = threadIdx.x;
    int lane = tid & 63, wave = tid >> 6;
    int wm = (wave & 1) * 64, wn = (wave >> 1) * 64;
    int q = lane >> 4, r16 = lane & 15;
    f32x4 acc[4][4];
    #pragma unroll
    for (int i = 0; i < 4; ++i)
        #pragma unroll
        for (int j = 0; j < 4; ++j) acc[i][j] = (f32x4){0.f, 0.f, 0.f, 0.f};

    // chunk ids (16B units): c0 = tid, c1 = 256+tid; chunk c -> row c>>2, k8 = (c&3)*8
    int c0 = tid, c1 = 256 + tid;
    int m0c = c0 >> 2, k0c = (c0 & 3) * 8;
    int m1c = c1 >> 2, k1c = (c1 & 3) * 8;
    int tok0 = aidx[gr + min(m0c, valid - 1)];
    int tok1 = aidx[gr + min(m1c, valid - 1)];
    const unsigned short* ga0 = xb + (size_t)tok0 * D_MODEL + k0c;
    const unsigned short* ga1 = xb + (size_t)tok1 * D_MODEL + k1c;
    const unsigned short* gb0 = w1t + ((size_t)(e * DFFN + n0 + m0c)) * D_MODEL + k0c;
    const unsigned short* gb1 = w1t + ((size_t)(e * DFFN + n0 + m1c)) * D_MODEL + k1c;
    unsigned short* lA0 = As + c0 * 8;
    unsigned short* lA1 = As + c1 * 8;
    unsigned short* lB0 = Bs + c0 * 8;
    unsigned short* lB1 = Bs + c1 * 8;

    for (int kt = 0; kt < D_MODEL / BK; ++kt) {
        int kofs = kt * BK;
        gll16(ga0 + kofs, lA0);
        gll16(ga1 + kofs, lA1);
        gll16(gb0 + kofs, lB0);
        gll16(gb1 + kofs, lB1);
        __syncthreads();
        bf16x8 af[4], bfr[4];
        #pragma unroll
        for (int im = 0; im < 4; ++im)
            af[im] = *(const bf16x8*)&As[(wm + im*16 + r16)*BK + q*8];
        #pragma unroll
        for (int in = 0; in < 4; ++in)
            bfr[in] = *(const bf16x8*)&Bs[(wn + in*16 + r16)*BK + q*8];
        #pragma unroll
        for (int im = 0; im < 4; ++im)
            #pragma unroll
            for (int in = 0; in < 4; ++in)
                acc[im][in] = __builtin_amdgcn_mfma_f32_16x16x32_bf16(af[im], bfr[in], acc[im][in], 0, 0, 0);
        __syncthreads();
    }
    #pragma unroll
    for (int im = 0; im < 4; ++im) {
        #pragma unroll
        for (int reg = 0; reg < 4; ++reg) {
            int m = wm + im*16 + q*4 + reg;
            if (m < valid) {
                size_t rowbase = (size_t)(gr + m) * DFFN + n0 + wn;
                #pragma unroll
                for (int in = 0; in < 4; ++in) {
                    float v = acc[im][in][reg];
                    float g = 0.5f * v * (1.0f + erff(v * 0.70710678118654752f));
                    H[rowbase + in*16 + r16] = f2bf(g);
                }
            }
        }
    }
}

// ---------------- GEMM2: out[t] += w * (H_row @ W2_e) ----------------
__global__ __launch_bounds__(256) void gemm2_kernel(
    const unsigned short* __restrict__ H, const unsigned short* __restrict__ w2t,
    const int* __restrict__ aidx, const float* __restrict__ aw,
    const int* __restrict__ tmap, const int* __restrict__ ntiles,
    float* __restrict__ out)
{
    int tile = blockIdx.y;
    if (tile >= *ntiles) return;
    int e     = tmap[tile*4+0];
    int gr    = tmap[tile*4+1];
    int valid = tmap[tile*4+2];
    int n0 = blockIdx.x * BN;
    __shared__ unsigned short As[BM*BK];
    __shared__ unsigned short Bs[BN*BK];
    int tid = threadIdx.x;
    int lane = tid & 63, wave = tid >> 6;
    int wm = (wave & 1) * 64, wn = (wave >> 1) * 64;
    int q = lane >> 4, r16 = lane & 15;
    f32x4 acc[4][4];
    #pragma unroll
    for (int i = 0; i < 4; ++i)
        #pragma unroll
        for (int j = 0; j < 4; ++j) acc[i][j] = (f32x4){0.f, 0.f, 0.f, 0.f};

    int c0 = tid, c1 = 256 + tid;
    int m0c = c0 >> 2, k0c = (c0 & 3) * 8;
    int m1c = c1 >> 2, k1c = (c1 & 3) * 8;
    const unsigned short* ga0 = H + (size_t)(gr + min(m0c, valid - 1)) * DFFN + k0c;
    const unsigned short* ga1 = H + (size_t)(gr + min(m1c, valid - 1)) * DFFN + k1c;
    const unsigned short* gb0 = w2t + (size_t)e * (DFFN * D_MODEL) + (size_t)(n0 + m0c) * DFFN + k0c;
    const unsigned short* gb1 = w2t + (size_t)e * (DFFN * D_MODEL) + (size_t)(n0 + m1c) * DFFN + k1c;
    unsigned short* lA0 = As + c0 * 8;
    unsigned short* lA1 = As + c1 * 8;
    unsigned short* lB0 = Bs + c0 * 8;
    unsigned short* lB1 = Bs + c1 * 8;

    for (int kt = 0; kt < DFFN / BK; ++kt) {
        int kofs = kt * BK;
        gll16(ga0 + kofs, lA0);
        gll16(ga1 + kofs, lA1);
        gll16(gb0 + kofs, lB0);
        gll16(gb1 + kofs, lB1);
        __syncthreads();
        bf16x8 af[4], bfr[4];
        #pragma unroll
        for (int im = 0; im < 4; ++im)
            af[im] = *(const bf16x8*)&As[(wm + im*16 + r16)*BK + q*8];
        #pragma unroll
        for (int in = 0; in < 4; ++in)
            bfr[in] = *(const bf16x8*)&Bs[(wn + in*16 + r16)*BK + q*8];
        #pragma unroll
        for (int im = 0; im < 4; ++im)
            #pragma unroll
            for (int in = 0; in < 4; ++in)
                acc[im][in] = __builtin_amdgcn_mfma_f32_16x16x32_bf16(af[im], bfr[in], acc[im][in], 0, 0, 0);
        __syncthreads();
    }
    #pragma unroll
    for (int im = 0; im < 4; ++im) {
        #pragma unroll
        for (int reg = 0; reg < 4; ++reg) {
            int m = wm + im*16 + q*4 + reg;
            if (m < valid) {
                int t = aidx[gr + m];
                float w = aw[gr + m];
                float* orow = out + (size_t)t*D_MODEL + n0 + wn;
                #pragma unroll
                for (int in = 0; in < 4; ++in)
                    unsafeAtomicAdd(&orow[in*16 + r16], w * acc[im][in][reg]);
            }
        }
    }
}

extern "C" void kernel_launch(void* const* d_in, const int* in_sizes, int n_in,
                              void* d_out, int out_size, void* d_ws, size_t ws_size,
                              hipStream_t stream)
{
    const float* x  = (const float*)d_in[0];
    const float* rw = (const float*)d_in[1];
    const float* w1 = (const float*)d_in[2];
    const float* w2 = (const float*)d_in[3];
    float* out = (float*)d_out;
    char* ws = (char*)d_ws;
    float* zsum   = (float*)(ws + WS_ZSUM);
    float* psum   = (float*)(ws + WS_PSUM);
    int*   counts = (int*)(ws + WS_COUNTS);
    int*   cursor = (int*)(ws + WS_CURSOR);
    int*   offs   = (int*)(ws + WS_OFFS);
    int*   ntiles = (int*)(ws + WS_NTILES);
    int*   tmap   = (int*)(ws + WS_TMAP);
    int*   sel    = (int*)(ws + WS_SEL);
    float* wgt    = (float*)(ws + WS_WGT);
    int*   aidx   = (int*)(ws + WS_AIDX);
    float* aw     = (float*)(ws + WS_AW);
    unsigned short* xb  = (unsigned short*)(ws + WS_XB);
    unsigned short* w1t = (unsigned short*)(ws + WS_W1T);
    unsigned short* w2t = (unsigned short*)(ws + WS_W2T);
    unsigned short* H   = (unsigned short*)(ws + WS_H);

    hipMemsetAsync(d_out, 0, (size_t)T_TOK * D_MODEL * sizeof(float), stream);
    hipMemsetAsync(ws, 0, 256, stream);

    cvt_x_kernel<<<T_TOK*D_MODEL/(256*8), 256, 0, stream>>>(x, xb);
    // W1: [K=1024][E*N=16384] -> [16384][1024]
    transpose_cvt_kernel<<<dim3(16384/64, 1024/64, 1), 256, 0, stream>>>(w1, w1t, 1024, 16384);
    // W2: per expert [K=2048][N=1024] -> [1024][2048]
    transpose_cvt_kernel<<<dim3(1024/64, 2048/64, 8), 256, 0, stream>>>(w2, w2t, 2048, 1024);

    router_kernel<<<T_TOK/32, 256, 0, stream>>>(x, rw, zsum, psum, counts, sel, wgt);
    finalize_kernel<<<1, 64, 0, stream>>>(counts, psum, zsum, offs, ntiles, tmap,
                                          out + (size_t)T_TOK * D_MODEL);
    scatter_kernel<<<T_TOK/256, 256, 0, stream>>>(sel, wgt, offs, cursor, aidx, aw);
    gemm1_kernel<<<dim3(DFFN/BN, TILE_MAX), 256, 0, stream>>>(xb, w1t, aidx, tmap, ntiles, H);
    gemm2_kernel<<<dim3(D_MODEL/BN, TILE_MAX), 256, 0, stream>>>(H, w2t, aidx, aw, tmap, ntiles, out);
}

// Round 3
// 597.195 us; speedup vs baseline: 1.1942x; 1.0268x over previous
//
#include <hip/hip_runtime.h>
#include <hip/hip_bf16.h>
#include <math.h>

#define T_TOK   8192
#define D_MODEL 1024
#define DFFN    2048
#define N_EXP   8
#define NASSIGN (T_TOK*2)

#define BM 128
#define BN 128
#define BK 64
#define TILE_MAX 144

// ---- workspace layout (byte offsets) ----
#define WS_ZSUM     0        // float
#define WS_PSUM     4        // 8 floats
#define WS_COUNTS   64       // 8 ints
#define WS_CURSOR   96       // 8 ints
#define WS_OFFS     128      // 8 ints
#define WS_NTILES   160      // int
#define WS_TMAP     256      // TILE_MAX * 4 ints (e, gr, valid, pad)
#define WS_SEL      4096     // NASSIGN ints
#define WS_WGT      69632    // NASSIGN floats
#define WS_AIDX     135168   // NASSIGN ints
#define WS_AW       200704   // NASSIGN floats
#define WS_XB       266240                    // T_TOK*D_MODEL bf16   (16 MB)
#define WS_W1T      (WS_XB + 16777216)        // [e][n][k] bf16       (32 MB)
#define WS_W2T      (WS_W1T + 33554432)       // [e][n][k] bf16       (32 MB)
#define WS_H        (WS_W2T + 33554432)       // NASSIGN*DFFN bf16    (64 MB)
// total ≈ 151.3 MB

typedef __attribute__((ext_vector_type(8))) short bf16x8;
typedef __attribute__((ext_vector_type(4))) float f32x4;
typedef __attribute__((ext_vector_type(4))) unsigned int u32x4;

static __device__ __forceinline__ unsigned short f2bf(float f) {
    unsigned int u = __builtin_bit_cast(unsigned int, f);
    u += 0x7fffu + ((u >> 16) & 1u);
    return (unsigned short)(u >> 16);
}

// async global->LDS, 16B per lane; LDS side must be wave-base + lane*16.
static __device__ __forceinline__ void gll16(const unsigned short* g, unsigned short* l) {
    __builtin_amdgcn_global_load_lds(
        (const __attribute__((address_space(1))) unsigned int*)g,
        (__attribute__((address_space(3))) unsigned int*)l, 16, 0, 0);
}

// LDS element offset of fragment chunk (row, kc) under the XOR swizzle.
// kc = k/8 in [0,8). Chunk (row,kc) sits at slot row*8 + (kc ^ (row&7)).
static __device__ __forceinline__ int frag_off(int row, int kc) {
    return (row * 8 + (kc ^ (row & 7))) * 8;
}

// in: [E][K][N] fp32 -> out: [E][N][K] bf16 (64x64 tiles)
__global__ __launch_bounds__(256) void transpose_cvt_kernel(
    const float* __restrict__ in, unsigned short* __restrict__ out, int K, int N)
{
    int e = blockIdx.z;
    const float* inp = in + (size_t)e * K * N;
    unsigned short* outp = out + (size_t)e * K * N;
    __shared__ unsigned short tile[64][68];
    int k0 = blockIdx.y * 64, n0 = blockIdx.x * 64;
    int tid = threadIdx.x;
    int r = tid >> 4, c4 = (tid & 15) * 4;
    #pragma unroll
    for (int p = 0; p < 4; ++p) {
        int k = r + p * 16;
        float4 v = *(const float4*)(inp + (size_t)(k0 + k) * N + n0 + c4);
        tile[k][c4+0] = f2bf(v.x);
        tile[k][c4+1] = f2bf(v.y);
        tile[k][c4+2] = f2bf(v.z);
        tile[k][c4+3] = f2bf(v.w);
    }
    __syncthreads();
    int n = tid >> 2, kc = (tid & 3) * 16;
    unsigned short t[16];
    #pragma unroll
    for (int j = 0; j < 16; ++j) t[j] = tile[kc + j][n];
    unsigned short* o = outp + (size_t)(n0 + n) * K + k0 + kc;
    *(u32x4*)o       = *(u32x4*)t;
    *(u32x4*)(o + 8) = *(u32x4*)(t + 8);
}

// ---------------- router (fused x -> bf16 conversion) ----------------
__global__ __launch_bounds__(256) void router_kernel(
    const float* __restrict__ x, const float* __restrict__ rw,
    float* zsum, float* psum, int* counts, int* sel, float* wgt,
    unsigned short* __restrict__ xb)
{
    __shared__ float xs[32*129];
    __shared__ float rs[8*129];
    __shared__ float lg[32*9];
    __shared__ float blk_p[8];
    __shared__ int   blk_c[8];
    __shared__ float blk_z;
    int tid = threadIdx.x;
    if (tid < 8) { blk_p[tid] = 0.f; blk_c[tid] = 0; }
    if (tid == 8) blk_z = 0.f;
    int tb = blockIdx.x * 32;
    int tt = tid >> 3, e = tid & 7;
    float acc = 0.f;
    for (int c = 0; c < 8; ++c) {
        int c0 = c * 128;
        #pragma unroll
        for (int p = 0; p < 16; ++p) {
            int flat = p * 256 + tid;
            int r = flat >> 7, col = flat & 127;
            xs[r*129 + col] = x[(size_t)(tb + r)*D_MODEL + c0 + col];
        }
        #pragma unroll
        for (int p = 0; p < 4; ++p) {
            int flat = p * 256 + tid;
            int er = flat >> 7, col = flat & 127;
            rs[er*129 + col] = rw[(size_t)er*D_MODEL + c0 + col];
        }
        __syncthreads();
        // fused conversion: write this x chunk out as bf16
        {
            int rr = tid >> 3, cc = (tid & 7) * 16;
            unsigned short tmp[16];
            #pragma unroll
            for (int j = 0; j < 16; ++j) tmp[j] = f2bf(xs[rr*129 + cc + j]);
            unsigned short* o = xb + (size_t)(tb + rr)*D_MODEL + c0 + cc;
            *(u32x4*)o       = *(u32x4*)tmp;
            *(u32x4*)(o + 8) = *(u32x4*)(tmp + 8);
        }
        #pragma unroll 8
        for (int i = 0; i < 128; ++i)
            acc += xs[tt*129 + i] * rs[e*129 + i];
        __syncthreads();
    }
    lg[tt*9 + e] = acc;
    __syncthreads();
    if (tid < 32) {
        int t = tb + tid;
        float l[8], p[8];
        float mx = -1e30f;
        #pragma unroll
        for (int j = 0; j < 8; ++j) { l[j] = lg[tid*9 + j]; mx = fmaxf(mx, l[j]); }
        float se = 0.f;
        #pragma unroll
        for (int j = 0; j < 8; ++j) { p[j] = expf(l[j] - mx); se += p[j]; }
        float inv = 1.f / se;
        #pragma unroll
        for (int j = 0; j < 8; ++j) p[j] *= inv;
        float lse = mx + logf(se);
        atomicAdd(&blk_z, lse*lse);
        #pragma unroll
        for (int j = 0; j < 8; ++j) atomicAdd(&blk_p[j], p[j]);
        int i0 = 0; float b0 = p[0];
        #pragma unroll
        for (int j = 1; j < 8; ++j) if (p[j] > b0) { b0 = p[j]; i0 = j; }
        int i1 = -1; float b1 = -1.f;
        #pragma unroll
        for (int j = 0; j < 8; ++j) if (j != i0 && p[j] > b1) { b1 = p[j]; i1 = j; }
        float s = b0 + b1;
        sel[t*2+0] = i0; sel[t*2+1] = i1;
        wgt[t*2+0] = b0 / s; wgt[t*2+1] = b1 / s;
        atomicAdd(&blk_c[i0], 1); atomicAdd(&blk_c[i1], 1);
    }
    __syncthreads();
    if (tid < 8) {
        atomicAdd(&counts[tid], blk_c[tid]);
        unsafeAtomicAdd(&psum[tid], blk_p[tid]);
    }
    if (tid == 8) unsafeAtomicAdd(zsum, blk_z);
}

// ---------------- offsets + tile map + aux-loss scalars ----------------
__global__ void finalize_kernel(const int* counts, const float* psum, const float* zsum,
                                int* offs, int* ntiles, int* tmap, float* out_tail)
{
    if (threadIdx.x != 0) return;
    int off = 0, nt = 0;
    float lb = 0.f;
    for (int e = 0; e < N_EXP; ++e) {
        int c = counts[e];
        offs[e] = off;
        for (int m0 = 0; m0 < c; m0 += BM) {
            tmap[nt*4+0] = e;
            tmap[nt*4+1] = off + m0;
            tmap[nt*4+2] = min(BM, c - m0);
            tmap[nt*4+3] = 0;
            nt++;
        }
        float fi = (float)c / (float)NASSIGN;
        out_tail[2 + e] = fi;
        lb += fi * (psum[e] / (float)T_TOK);
        off += c;
    }
    *ntiles = nt;
    out_tail[0] = zsum[0] / (float)T_TOK;
    out_tail[1] = (float)N_EXP * lb;
}

// ---------------- scatter tokens into per-expert segments ----------------
__global__ __launch_bounds__(256) void scatter_kernel(
    const int* __restrict__ sel, const float* __restrict__ wgt,
    const int* __restrict__ offs, int* cursor, int* aidx, float* aw)
{
    int t = blockIdx.x * 256 + threadIdx.x;
    if (t >= T_TOK) return;
    #pragma unroll
    for (int k = 0; k < 2; ++k) {
        int e = sel[t*2 + k];
        int pos = atomicAdd(&cursor[e], 1);
        int r = offs[e] + pos;
        aidx[r] = t;
        aw[r] = wgt[t*2 + k];
    }
}

// ---------------- GEMM1: H = gelu(Xg @ W1_e), bf16 out ----------------
// BK=64, XOR-swizzled LDS chunks, 8x gll16 per thread per iter.
__global__ __launch_bounds__(256) void gemm1_kernel(
    const unsigned short* __restrict__ xb, const unsigned short* __restrict__ w1t,
    const int* __restrict__ aidx, const int* __restrict__ tmap,
    const int* __restrict__ ntiles, unsigned short* __restrict__ H)
{
    int tile = blockIdx.y;
    if (tile >= *ntiles) return;
    int e     = tmap[tile*4+0];
    int gr    = tmap[tile*4+1];
    int valid = tmap[tile*4+2];
    int n0 = blockIdx.x * BN;
    __shared__ unsigned short As[BM*BK];
    __shared__ unsigned short Bs[BN*BK];
    int tid = threadIdx.x;
    int lane = tid & 63, wave = tid >> 6;
    int wm = (wave & 1) * 64, wn = (wave >> 1) * 64;
    int q = lane >> 4, r16 = lane & 15;
    f32x4 acc[4][4];
    #pragma unroll
    for (int i = 0; i < 4; ++i)
        #pragma unroll
        for (int j = 0; j < 4; ++j) acc[i][j] = (f32x4){0.f, 0.f, 0.f, 0.f};

    // staging: 4 chunks per matrix per thread. chunk c -> row c>>3, lds-kc c&7,
    // global kc = (c&7) ^ (row&7)  (XOR swizzle; LDS side stays lane-contiguous)
    const unsigned short* aga[4];
    const unsigned short* bga[4];
    unsigned short* ldsA[4];
    unsigned short* ldsB[4];
    #pragma unroll
    for (int j = 0; j < 4; ++j) {
        int c = tid + j*256;
        int m = c >> 3, kl = c & 7;
        int kg = kl ^ (m & 7);
        int tok = aidx[gr + min(m, valid - 1)];
        aga[j] = xb + (size_t)tok * D_MODEL + kg*8;
        bga[j] = w1t + ((size_t)(e * DFFN + n0 + m)) * D_MODEL + kg*8;
        ldsA[j] = As + c*8;
        ldsB[j] = Bs + c*8;
    }

    for (int kt = 0; kt < D_MODEL / BK; ++kt) {
        int ko = kt * BK;
        #pragma unroll
        for (int j = 0; j < 4; ++j) gll16(aga[j] + ko, ldsA[j]);
        #pragma unroll
        for (int j = 0; j < 4; ++j) gll16(bga[j] + ko, ldsB[j]);
        __syncthreads();
        #pragma unroll
        for (int kh = 0; kh < 2; ++kh) {
            bf16x8 af[4], bfr[4];
            #pragma unroll
            for (int im = 0; im < 4; ++im)
                af[im] = *(const bf16x8*)&As[frag_off(wm + im*16 + r16, q + 4*kh)];
            #pragma unroll
            for (int in = 0; in < 4; ++in)
                bfr[in] = *(const bf16x8*)&Bs[frag_off(wn + in*16 + r16, q + 4*kh)];
            #pragma unroll
            for (int im = 0; im < 4; ++im)
                #pragma unroll
                for (int in = 0; in < 4; ++in)
                    acc[im][in] = __builtin_amdgcn_mfma_f32_16x16x32_bf16(af[im], bfr[in], acc[im][in], 0, 0, 0);
        }
        __syncthreads();
    }
    #pragma unroll
    for (int im = 0; im < 4; ++im) {
        #pragma unroll
        for (int reg = 0; reg < 4; ++reg) {
            int m = wm + im*16 + q*4 + reg;
            if (m < valid) {
                size_t rowbase = (size_t)(gr + m) * DFFN + n0 + wn;
                #pragma unroll
                for (int in = 0; in < 4; ++in) {
                    float v = acc[im][in][reg];
                    float g = 0.5f * v * (1.0f + erff(v * 0.70710678118654752f));
                    H[rowbase + in*16 + r16] = f2bf(g);
                }
            }
        }
    }
}

// ---------------- GEMM2: out[t] += w * (H_row @ W2_e) ----------------
__global__ __launch_bounds__(256) void gemm2_kernel(
    const unsigned short* __restrict__ H, const unsigned short* __restrict__ w2t,
    const int* __restrict__ aidx, const float* __restrict__ aw,
    const int* __restrict__ tmap, const int* __restrict__ ntiles,
    float* __restrict__ out)
{
    int tile = blockIdx.y;
    if (tile >= *ntiles) return;
    int e     = tmap[tile*4+0];
    int gr    = tmap[tile*4+1];
    int valid = tmap[tile*4+2];
    int n0 = blockIdx.x * BN;
    __shared__ unsigned short As[BM*BK];
    __shared__ unsigned short Bs[BN*BK];
    int tid = threadIdx.x;
    int lane = tid & 63, wave = tid >> 6;
    int wm = (wave & 1) * 64, wn = (wave >> 1) * 64;
    int q = lane >> 4, r16 = lane & 15;
    f32x4 acc[4][4];
    #pragma unroll
    for (int i = 0; i < 4; ++i)
        #pragma unroll
        for (int j = 0; j < 4; ++j) acc[i][j] = (f32x4){0.f, 0.f, 0.f, 0.f};

    const unsigned short* aga[4];
    const unsigned short* bga[4];
    unsigned short* ldsA[4];
    unsigned short* ldsB[4];
    #pragma unroll
    for (int j = 0; j < 4; ++j) {
        int c = tid + j*256;
        int m = c >> 3, kl = c & 7;
        int kg = kl ^ (m & 7);
        aga[j] = H + (size_t)(gr + min(m, valid - 1)) * DFFN + kg*8;
        bga[j] = w2t + (size_t)e * (DFFN * D_MODEL) + (size_t)(n0 + m) * DFFN + kg*8;
        ldsA[j] = As + c*8;
        ldsB[j] = Bs + c*8;
    }

    for (int kt = 0; kt < DFFN / BK; ++kt) {
        int ko = kt * BK;
        #pragma unroll
        for (int j = 0; j < 4; ++j) gll16(aga[j] + ko, ldsA[j]);
        #pragma unroll
        for (int j = 0; j < 4; ++j) gll16(bga[j] + ko, ldsB[j]);
        __syncthreads();
        #pragma unroll
        for (int kh = 0; kh < 2; ++kh) {
            bf16x8 af[4], bfr[4];
            #pragma unroll
            for (int im = 0; im < 4; ++im)
                af[im] = *(const bf16x8*)&As[frag_off(wm + im*16 + r16, q + 4*kh)];
            #pragma unroll
            for (int in = 0; in < 4; ++in)
                bfr[in] = *(const bf16x8*)&Bs[frag_off(wn + in*16 + r16, q + 4*kh)];
            #pragma unroll
            for (int im = 0; im < 4; ++im)
                #pragma unroll
                for (int in = 0; in < 4; ++in)
                    acc[im][in] = __builtin_amdgcn_mfma_f32_16x16x32_bf16(af[im], bfr[in], acc[im][in], 0, 0, 0);
        }
        __syncthreads();
    }
    #pragma unroll
    for (int im = 0; im < 4; ++im) {
        #pragma unroll
        for (int reg = 0; reg < 4; ++reg) {
            int m = wm + im*16 + q*4 + reg;
            if (m < valid) {
                int t = aidx[gr + m];
                float w = aw[gr + m];
                float* orow = out + (size_t)t*D_MODEL + n0 + wn;
                #pragma unroll
                for (int in = 0; in < 4; ++in)
                    unsafeAtomicAdd(&orow[in*16 + r16], w * acc[im][in][reg]);
            }
        }
    }
}

extern "C" void kernel_launch(void* const* d_in, const int* in_sizes, int n_in,
                              void* d_out, int out_size, void* d_ws, size_t ws_size,
                              hipStream_t stream)
{
    const float* x  = (const float*)d_in[0];
    const float* rw = (const float*)d_in[1];
    const float* w1 = (const float*)d_in[2];
    const float* w2 = (const float*)d_in[3];
    float* out = (float*)d_out;
    char* ws = (char*)d_ws;
    float* zsum   = (float*)(ws + WS_ZSUM);
    float* psum   = (float*)(ws + WS_PSUM);
    int*   counts = (int*)(ws + WS_COUNTS);
    int*   cursor = (int*)(ws + WS_CURSOR);
    int*   offs   = (int*)(ws + WS_OFFS);
    int*   ntiles = (int*)(ws + WS_NTILES);
    int*   tmap   = (int*)(ws + WS_TMAP);
    int*   sel    = (int*)(ws + WS_SEL);
    float* wgt    = (float*)(ws + WS_WGT);
    int*   aidx   = (int*)(ws + WS_AIDX);
    float* aw     = (float*)(ws + WS_AW);
    unsigned short* xb  = (unsigned short*)(ws + WS_XB);
    unsigned short* w1t = (unsigned short*)(ws + WS_W1T);
    unsigned short* w2t = (unsigned short*)(ws + WS_W2T);
    unsigned short* H   = (unsigned short*)(ws + WS_H);

    hipMemsetAsync(d_out, 0, (size_t)T_TOK * D_MODEL * sizeof(float), stream);
    hipMemsetAsync(ws, 0, 256, stream);

    // W1: [K=1024][E*N=16384] -> [16384][1024]
    transpose_cvt_kernel<<<dim3(16384/64, 1024/64, 1), 256, 0, stream>>>(w1, w1t, 1024, 16384);
    // W2: per expert [K=2048][N=1024] -> [1024][2048]
    transpose_cvt_kernel<<<dim3(1024/64, 2048/64, 8), 256, 0, stream>>>(w2, w2t, 2048, 1024);

    router_kernel<<<T_TOK/32, 256, 0, stream>>>(x, rw, zsum, psum, counts, sel, wgt, xb);
    finalize_kernel<<<1, 64, 0, stream>>>(counts, psum, zsum, offs, ntiles, tmap,
                                          out + (size_t)T_TOK * D_MODEL);
    scatter_kernel<<<T_TOK/256, 256, 0, stream>>>(sel, wgt, offs, cursor, aidx, aw);
    gemm1_kernel<<<dim3(DFFN/BN, TILE_MAX), 256, 0, stream>>>(xb, w1t, aidx, tmap, ntiles, H);
    gemm2_kernel<<<dim3(D_MODEL/BN, TILE_MAX), 256, 0, stream>>>(H, w2t, aidx, aw, tmap, ntiles, out);
}